// Round 6
// baseline (1419.855 us; speedup 1.0000x reference)
//
#include <hip/hip_runtime.h>
#include <math.h>

// ---------------- device helpers ----------------

__device__ __forceinline__ float elu_f(float x) {
    return x > 0.f ? x : expm1f(x);
}

// ---------------- node MLP ----------------

__global__ void mlp_kernel(const float* __restrict__ x,
                           const float* __restrict__ A, const float* __restrict__ ab,
                           const float* __restrict__ B, const float* __restrict__ bb,
                           float* __restrict__ out, int n) {
    __shared__ float sA[23 * 23], sB[23 * 23], sa[23], sb[23];
    for (int t = threadIdx.x; t < 23 * 23; t += blockDim.x) { sA[t] = A[t]; sB[t] = B[t]; }
    if (threadIdx.x < 23) { sa[threadIdx.x] = ab[threadIdx.x]; sb[threadIdx.x] = bb[threadIdx.x]; }
    __syncthreads();
    int i = blockIdx.x * blockDim.x + threadIdx.x;
    if (i >= n) return;
    float xi[23], h1[23];
    #pragma unroll
    for (int j = 0; j < 23; j++) xi[j] = x[(size_t)i * 23 + j];
    #pragma unroll
    for (int o = 0; o < 23; o++) {
        float acc = sa[o];
        #pragma unroll
        for (int j = 0; j < 23; j++) acc = fmaf(xi[j], sA[j * 23 + o], acc);
        h1[o] = elu_f(acc);
    }
    #pragma unroll
    for (int o = 0; o < 23; o++) {
        float acc = sb[o];
        #pragma unroll
        for (int j = 0; j < 23; j++) acc = fmaf(h1[j], sB[j * 23 + o], acc);
        out[(size_t)i * 23 + o] = elu_f(acc);
    }
}

// ---------------- register-tiled multi-output projection (GEMM) ----------------
// FUSED=false: each mat m writes its own buffer o_m with row stride OUTW.
// FUSED=true : all mats write one buffer o0 with row stride WTOT at col m*OUTW+cc
//              (interleaved per-node layout, e.g. k|v rows adjacent).
template<int IN, int Kc, int OUTW, int M, int TY, bool FUSED>
__global__ void proj_tiled_kernel(const float* __restrict__ in, int n,
    const float* __restrict__ W0, const float* __restrict__ b0, float* __restrict__ o0,
    const float* __restrict__ W1, const float* __restrict__ b1, float* __restrict__ o1,
    const float* __restrict__ W2, const float* __restrict__ b2, float* __restrict__ o2,
    const float* __restrict__ W3, const float* __restrict__ b3, float* __restrict__ o3) {
    constexpr int WTOT = M * OUTW;
    constexpr int CG   = WTOT / 8;
    constexpr int BN   = TY * 4;
    constexpr int SAW  = BN + 4;
    constexpr int NT   = CG * TY;
    static_assert(IN % Kc == 0, "Kc must divide IN");
    static_assert(WTOT % 8 == 0 && OUTW % 4 == 0, "col alignment");
    __shared__ float sA[Kc][SAW];
    __shared__ float sB[Kc][WTOT];

    const int tid = threadIdx.x;
    const int tx = tid % CG;
    const int ty = tid / CG;
    const int node0 = blockIdx.x * BN;

    const int colA = tx * 4;
    const int colB = WTOT / 2 + tx * 4;
    const int matA = colA / OUTW, ccA = colA % OUTW;
    const int matB = colB / OUTW, ccB = colB % OUTW;
    const float* bA = (matA == 0 ? b0 : matA == 1 ? b1 : matA == 2 ? b2 : b3);
    const float* bB = (matB == 0 ? b0 : matB == 1 ? b1 : matB == 2 ? b2 : b3);
    float*       oA = (matA == 0 ? o0 : matA == 1 ? o1 : matA == 2 ? o2 : o3);
    float*       oB = (matB == 0 ? o0 : matB == 1 ? o1 : matB == 2 ? o2 : o3);

    float acc[4][8];
    #pragma unroll
    for (int i = 0; i < 4; i++) {
        #pragma unroll
        for (int c = 0; c < 4; c++) { acc[i][c] = bA[ccA + c]; acc[i][4 + c] = bB[ccB + c]; }
    }

    for (int k0 = 0; k0 < IN; k0 += Kc) {
        for (int t = tid; t < Kc * BN; t += NT) {
            int j = t / BN, nn = t - j * BN;
            int g = node0 + nn;
            sA[j][nn] = (g < n) ? in[(size_t)g * IN + k0 + j] : 0.f;
        }
        for (int t = tid; t < Kc * WTOT; t += NT) {
            int j = t / WTOT, c = t - j * WTOT;
            int m = c / OUTW, cm = c - m * OUTW;
            const float* Wp = (m == 0 ? W0 : m == 1 ? W1 : m == 2 ? W2 : W3);
            sB[j][c] = Wp[(size_t)(k0 + j) * OUTW + cm];
        }
        __syncthreads();
        #pragma unroll 8
        for (int j = 0; j < Kc; j++) {
            float4 a  = *(const float4*)&sA[j][ty * 4];
            float4 v0 = *(const float4*)&sB[j][colA];
            float4 v1 = *(const float4*)&sB[j][colB];
            float av[4] = {a.x, a.y, a.z, a.w};
            float bv[8] = {v0.x, v0.y, v0.z, v0.w, v1.x, v1.y, v1.z, v1.w};
            #pragma unroll
            for (int i = 0; i < 4; i++)
                #pragma unroll
                for (int c = 0; c < 8; c++)
                    acc[i][c] = fmaf(av[i], bv[c], acc[i][c]);
        }
        __syncthreads();
    }

    #pragma unroll
    for (int i = 0; i < 4; i++) {
        int g = node0 + ty * 4 + i;
        if (g >= n) continue;
        if constexpr (FUSED) {
            *(float4*)(o0 + (size_t)g * WTOT + colA) = make_float4(acc[i][0], acc[i][1], acc[i][2], acc[i][3]);
            *(float4*)(o0 + (size_t)g * WTOT + colB) = make_float4(acc[i][4], acc[i][5], acc[i][6], acc[i][7]);
        } else {
            *(float4*)(oA + (size_t)g * OUTW + ccA) = make_float4(acc[i][0], acc[i][1], acc[i][2], acc[i][3]);
            *(float4*)(oB + (size_t)g * OUTW + ccB) = make_float4(acc[i][4], acc[i][5], acc[i][6], acc[i][7]);
        }
    }
}

// ---------------- CSR build ----------------

__global__ void zero2_kernel(int* __restrict__ a, int* __restrict__ b, int n) {
    int i = blockIdx.x * blockDim.x + threadIdx.x;
    if (i < n) { a[i] = 0; b[i] = 0; }
}

__global__ void count_kernel(const int* __restrict__ dst, int* __restrict__ cnt, int nE) {
    int e = blockIdx.x * blockDim.x + threadIdx.x;
    if (e < nE) atomicAdd(&cnt[dst[e]], 1);
}

__global__ void scan_block_kernel(int* __restrict__ cnt, int* __restrict__ bsum, int n) {
    __shared__ int sdat[256];
    int i = blockIdx.x * 256 + threadIdx.x;
    int v = (i < n) ? cnt[i] : 0;
    sdat[threadIdx.x] = v;
    __syncthreads();
    for (int off = 1; off < 256; off <<= 1) {
        int t = (threadIdx.x >= (unsigned)off) ? sdat[threadIdx.x - off] : 0;
        __syncthreads();
        sdat[threadIdx.x] += t;
        __syncthreads();
    }
    if (i < n) cnt[i] = sdat[threadIdx.x] - v;
    if (threadIdx.x == 255) bsum[blockIdx.x] = sdat[255];
}

__global__ void scan_bsum_kernel(int* __restrict__ bsum, int nb) {
    __shared__ int s[1024];
    int i = threadIdx.x;
    int v = (i < nb) ? bsum[i] : 0;
    s[i] = v;
    __syncthreads();
    for (int off = 1; off < 1024; off <<= 1) {
        int t = (i >= off) ? s[i - off] : 0;
        __syncthreads();
        s[i] += t;
        __syncthreads();
    }
    if (i < nb) bsum[i] = s[i] - v;
}

__global__ void finalize_rp_kernel(const int* __restrict__ cnt, const int* __restrict__ bsum,
                                   int* __restrict__ rp, int n, int nE) {
    int i = blockIdx.x * blockDim.x + threadIdx.x;
    if (i < n) rp[i] = cnt[i] + bsum[i >> 8];
    if (i == n) rp[n] = nE;
}

__global__ void scatter_kernel(const int* __restrict__ src, const int* __restrict__ dst,
                               const int* __restrict__ rp, int* __restrict__ cur,
                               int2* __restrict__ seS, int nE) {
    int e = blockIdx.x * blockDim.x + threadIdx.x;
    if (e >= nE) return;
    int d = dst[e];
    int pos = rp[d] + atomicAdd(&cur[d], 1);
    seS[pos] = make_int2(src[e], e);
}

// ---------------- fused TransformerConv ----------------
// Persistent chunked waves. LANE-SPLIT edge parallelism: the 64-lane wave is
// divided into NSPLIT = 64/LSPLIT sub-groups, each processing its own edge
// stream (p0+sub, step NSPLIT) with an independent online-softmax state
// (m,l,acc) per lane. Streams are merged at node end via shfl_xor log-sum-exp
// merge (NaN-guarded for empty streams). One load instruction fetches NSPLIT
// independent random kv rows -> NSPLITx memory-level parallelism with ZERO
// shadow registers (rounds 2-5: every register-prefetch variant spilled).
// We table lives in LDS (frees 21+ VGPRs; reads are broadcast within a
// sub-group and hide under gather latency). No __launch_bounds__ (round 5:
// forcing occupancy made the allocator spill baseline state).
// VMAT layout: interleaved kv rows, row stride 2*HC, v at offset +HC.
template<int IN, int C, int LSPLIT, bool VMAT, bool QMAT, bool DOELU>
__global__ void conv_fused_kernel(const float* __restrict__ feat,
                                  const float* __restrict__ Wq, const float* __restrict__ qb,
                                  const float* __restrict__ Wv, const float* __restrict__ vb,
                                  const float* __restrict__ kmat, const float* __restrict__ qmat,
                                  const float* __restrict__ ea, const float* __restrict__ We,
                                  const int* __restrict__ rp, const int2* __restrict__ seS,
                                  float* __restrict__ out, int n, float scale, int chunk) {
    constexpr int HC = 8 * C;
    constexpr int CPL = HC / LSPLIT;       // channels per lane
    constexpr int NSPLIT = 64 / LSPLIT;    // concurrent edges per wave
    constexpr int LPG = C / CPL;           // lanes per head group
    static_assert(HC % LSPLIT == 0 && C % CPL == 0, "split alignment");

    __shared__ float sWe[7 * HC];
    __shared__ float sWv[VMAT ? 1 : IN * HC];
    for (int t = threadIdx.x; t < 7 * HC; t += blockDim.x) sWe[t] = We[t];
    if constexpr (!VMAT) {
        for (int t = threadIdx.x; t < IN * HC; t += blockDim.x) sWv[t] = Wv[t];
    }
    __syncthreads();

    const int lane = threadIdx.x & 63;
    const int wid = (blockIdx.x * blockDim.x + threadIdx.x) >> 6;
    const int d0 = wid * chunk;
    const int dEnd = min(n, d0 + chunk);
    if (d0 >= dEnd) return;
    const int li = lane & (LSPLIT - 1);
    const int sub = lane / LSPLIT;
    const int ch0 = li * CPL;

    float vbr[CPL];
    if constexpr (!VMAT) {
        #pragma unroll
        for (int c = 0; c < CPL; c++) vbr[c] = vb[ch0 + c];
    }

    for (int d = d0; d < dEnd; d++) {
        float q[CPL];
        if constexpr (QMAT) {
            const float* qp = qmat + (size_t)d * HC + ch0;
            #pragma unroll
            for (int c = 0; c < CPL; c++) q[c] = qp[c];
        } else {
            #pragma unroll
            for (int c = 0; c < CPL; c++) q[c] = qb[ch0 + c];
            const float* fd = feat + (size_t)d * IN;
            for (int j = 0; j < IN; j++) {
                float f = fd[j];
                #pragma unroll
                for (int c = 0; c < CPL; c++)
                    q[c] = fmaf(f, Wq[(size_t)j * HC + ch0 + c], q[c]);
            }
        }

        float m = -INFINITY, l = 0.f, acc[CPL];
        #pragma unroll
        for (int c = 0; c < CPL; c++) acc[c] = 0.f;

        const int p0 = rp[d], p1 = rp[d + 1];

        if constexpr (VMAT) {
            for (int p = p0 + sub; p < p1; p += NSPLIT) {
                int2 se = seS[p];                      // uniform within sub-group
                const float* kp = kmat + (size_t)se.x * (2 * HC) + ch0;
                float kc[CPL], vc[CPL];
                #pragma unroll
                for (int c = 0; c < CPL; c++) kc[c] = kp[c];
                #pragma unroll
                for (int c = 0; c < CPL; c++) vc[c] = kp[HC + c];
                const float* ep = ea + (size_t)se.y * 7;
                float ec[7];
                #pragma unroll
                for (int j = 0; j < 7; j++) ec[j] = ep[j];

                float part = 0.f, tv[CPL];
                #pragma unroll
                for (int c = 0; c < CPL; c++) {
                    float t = 0.f;
                    #pragma unroll
                    for (int j = 0; j < 7; j++) t = fmaf(ec[j], sWe[j * HC + ch0 + c], t);
                    tv[c] = t;
                    part = fmaf(q[c], kc[c] + t, part);
                }
                if constexpr (LPG > 1) part += __shfl_xor(part, 1);
                if constexpr (LPG > 2) part += __shfl_xor(part, 2);
                if constexpr (LPG > 4) part += __shfl_xor(part, 4);
                float z = part * scale;
                float mn = fmaxf(m, z);
                float rs = expf(m - mn);
                float pw = expf(z - mn);
                l = l * rs + pw;
                #pragma unroll
                for (int c = 0; c < CPL; c++) acc[c] = fmaf(acc[c], rs, pw * (vc[c] + tv[c]));
                m = mn;
            }
            // merge the NSPLIT per-sub-group streams (log-sum-exp merge)
            #pragma unroll
            for (int off = LSPLIT; off < 64; off <<= 1) {
                float mo = __shfl_xor(m, off);
                float lo = __shfl_xor(l, off);
                float ao[CPL];
                #pragma unroll
                for (int c = 0; c < CPL; c++) ao[c] = __shfl_xor(acc[c], off);
                float mn = fmaxf(m, mo);
                float ra = (l  > 0.f) ? expf(m  - mn) : 0.f;
                float rb = (lo > 0.f) ? expf(mo - mn) : 0.f;
                l = l * ra + lo * rb;
                #pragma unroll
                for (int c = 0; c < CPL; c++) acc[c] = acc[c] * ra + ao[c] * rb;
                m = mn;
            }
        } else {
            // fallback (tier0 conv1, LSPLIT=64): v recomputed from LDS weights
            for (int p = p0; p < p1; p++) {
                int2 se = seS[p];
                int s = se.x, eid = se.y;
                const float* eav = ea + (size_t)eid * 7;
                float ev[7];
                #pragma unroll
                for (int j = 0; j < 7; j++) ev[j] = eav[j];
                const float* kp = kmat + (size_t)s * HC + ch0;
                float vv[CPL];
                float part = 0.f;
                #pragma unroll
                for (int c = 0; c < CPL; c++) {
                    float t = 0.f;
                    #pragma unroll
                    for (int j = 0; j < 7; j++) t = fmaf(ev[j], sWe[j * HC + ch0 + c], t);
                    part = fmaf(q[c], kp[c] + t, part);
                    vv[c] = t + vbr[c];
                }
                const float* fs = feat + (size_t)s * IN;
                for (int j = 0; j < IN; j++) {
                    float f = fs[j];
                    #pragma unroll
                    for (int c = 0; c < CPL; c++) vv[c] = fmaf(f, sWv[j * HC + ch0 + c], vv[c]);
                }
                if constexpr (LPG > 1) part += __shfl_xor(part, 1);
                if constexpr (LPG > 2) part += __shfl_xor(part, 2);
                if constexpr (LPG > 4) part += __shfl_xor(part, 4);
                float z = part * scale;
                float mn = fmaxf(m, z);
                float rs = expf(m - mn);
                float pw = expf(z - mn);
                l = l * rs + pw;
                #pragma unroll
                for (int c = 0; c < CPL; c++) acc[c] = fmaf(acc[c], rs, pw * vv[c]);
                m = mn;
            }
        }

        // output: skip row read late; only sub-group 0 writes
        float invl = (l > 0.f) ? 1.f / l : 0.f;
        float* op = out + (size_t)d * HC + ch0;
        if (sub == 0) {
            #pragma unroll
            for (int c = 0; c < CPL; c++) {
                float r = op[c] + acc[c] * invl;
                op[c] = DOELU ? elu_f(r) : r;
            }
        }
    }
}

// ---------------- head ----------------
__global__ void head_kernel(const float* __restrict__ h, const float* __restrict__ W1,
                            const float* __restrict__ b1, const float* __restrict__ W2,
                            const float* __restrict__ b2, float* __restrict__ out, int n) {
    __shared__ float sW1[64 * 20], sb1[20], sW2[20], sb2;
    for (int t = threadIdx.x; t < 64 * 20; t += blockDim.x) sW1[t] = W1[t];
    if (threadIdx.x < 20) { sb1[threadIdx.x] = b1[threadIdx.x]; sW2[threadIdx.x] = W2[threadIdx.x]; }
    if (threadIdx.x == 0) sb2 = b2[0];
    __syncthreads();
    int i = blockIdx.x * blockDim.x + threadIdx.x;
    if (i >= n) return;
    float hv[64];
    const float* hp = h + (size_t)i * 64;
    #pragma unroll
    for (int j = 0; j < 64; j++) hv[j] = elu_f(hp[j]);
    float acc2 = sb2;
    for (int o = 0; o < 20; o++) {
        float a = sb1[o];
        #pragma unroll
        for (int j = 0; j < 64; j++) a = fmaf(hv[j], sW1[j * 20 + o], a);
        acc2 = fmaf(elu_f(a), sW2[o], acc2);
    }
    out[i] = acc2;
}

__global__ void zero_out_kernel(float* __restrict__ out, int n) {
    int i = blockIdx.x * blockDim.x + threadIdx.x;
    if (i < n) out[i] = 0.f;
}

// ---------------- launcher ----------------

extern "C" void kernel_launch(void* const* d_in, const int* in_sizes, int n_in,
                              void* d_out, int out_size, void* d_ws, size_t ws_size,
                              hipStream_t stream) {
    const float* x   = (const float*)d_in[0];
    const int*   ei  = (const int*)d_in[1];
    const float* ea  = (const float*)d_in[2];
    const float* Aw  = (const float*)d_in[3];
    const float* Ab  = (const float*)d_in[4];
    const float* Bw  = (const float*)d_in[5];
    const float* Bb  = (const float*)d_in[6];
    const float* q1w = (const float*)d_in[7];  const float* q1b = (const float*)d_in[8];
    const float* k1w = (const float*)d_in[9];  const float* k1b = (const float*)d_in[10];
    const float* v1w = (const float*)d_in[11]; const float* v1b = (const float*)d_in[12];
    const float* e1w = (const float*)d_in[13];
    const float* s1w = (const float*)d_in[14]; const float* s1b = (const float*)d_in[15];
    const float* q2w = (const float*)d_in[16]; const float* q2b = (const float*)d_in[17];
    const float* k2w = (const float*)d_in[18]; const float* k2b = (const float*)d_in[19];
    const float* v2w = (const float*)d_in[20]; const float* v2b = (const float*)d_in[21];
    const float* e2w = (const float*)d_in[22];
    const float* s2w = (const float*)d_in[23]; const float* s2b = (const float*)d_in[24];
    const float* l1w = (const float*)d_in[25]; const float* l1b = (const float*)d_in[26];
    const float* l2w = (const float*)d_in[27]; const float* l2b = (const float*)d_in[28];

    const int n  = in_sizes[0] / 23;
    const int nE = in_sizes[1] / 2;
    const int* src = ei;
    const int* dst = ei + nE;
    float* out = (float*)d_out;
    const int B = 256;
    const int nb = (n + 255) / 256;

    // ---- workspace layout ----
    size_t fl_h1 = ((size_t)n * 23 + 3) & ~(size_t)3;
    size_t fl_o1 = (size_t)n * 192;
    size_t fl_kvA = (size_t)n * 384;   // tierA+: kv1 interleaved, later kv2|q2|o2
    size_t fl_kB  = (size_t)n * 192;   // tierB: k1, later kv2|o2
    size_t fl_q1  = (size_t)n * 192;   // tierA2 only: q1 projection
    size_t ints_total = 2 * (size_t)nE + ((size_t)n + 1) + n + n + 1024;

    size_t tierB_bytes  = (fl_h1 + fl_o1 + fl_kB) * 4 + ints_total * 4;
    size_t tierA_bytes  = (fl_h1 + fl_o1 + fl_kvA) * 4 + ints_total * 4;
    size_t tierA2_bytes = tierA_bytes + fl_q1 * 4;

    if (ws_size < tierB_bytes || nb > 1024) {
        zero_out_kernel<<<(out_size + B - 1) / B, B, 0, stream>>>(out, out_size);
        return;
    }
    const int tier = (ws_size >= tierA2_bytes) ? 2 : (ws_size >= tierA_bytes) ? 1 : 0;

    float* ws = (float*)d_ws;
    size_t off = 0;
    float* h1   = ws + off; off += fl_h1;
    float* o1   = ws + off; off += fl_o1;
    float* kbuf = ws + off; off += (tier >= 1 ? fl_kvA : fl_kB);
    float* q1buf = nullptr;
    if (tier == 2) { q1buf = ws + off; off += fl_q1; }
    // int area: seS first (8B-aligned since all float counts above are even)
    int2* seS = (int2*)(ws + off);
    int* ip = (int*)(seS + nE);
    int* rp   = ip; ip += (size_t)n + 1;
    int* cnt  = ip; ip += n;
    int* cur  = ip; ip += n;
    int* bsum = ip;

    // conv1: kv1 = kbuf (interleaved n x 384) for tier>=1; k-only (n x 192) tier0
    // conv2 buffers alias kbuf region (conv1 edge phase completes first):
    float* kv2   = kbuf;                                        // n x 128 interleaved
    float* q2buf = (tier >= 1) ? (kbuf + (size_t)n * 128) : nullptr;  // n x 64
    float* o2    = (tier >= 1) ? (kbuf + (size_t)n * 192) : (kbuf + (size_t)n * 128); // n x 64

    const float sc1 = 1.0f / sqrtf(24.0f);
    const float sc2 = 1.0f / sqrtf(8.0f);
    const float* np = nullptr;
    float* npw = nullptr;

    // ---- CSR build ----
    zero2_kernel<<<(n + B - 1) / B, B, 0, stream>>>(cnt, cur, n);
    count_kernel<<<(nE + B - 1) / B, B, 0, stream>>>(dst, cnt, nE);
    scan_block_kernel<<<nb, 256, 0, stream>>>(cnt, bsum, n);
    scan_bsum_kernel<<<1, 1024, 0, stream>>>(bsum, nb);
    finalize_rp_kernel<<<(n + 1 + B - 1) / B, B, 0, stream>>>(cnt, bsum, rp, n, nE);
    scatter_kernel<<<(nE + B - 1) / B, B, 0, stream>>>(src, dst, rp, cur, seS, nE);

    // ---- node MLP ----
    mlp_kernel<<<(n + B - 1) / B, B, 0, stream>>>(x, Aw, Ab, Bw, Bb, h1, n);

    const int gproj32 = (n + 31) / 32;
    const int gproj64 = (n + 63) / 64;

    // persistent conv grid
    const int CB = 2048;
    const int NW = CB * 4;
    const int chunk = (n + NW - 1) / NW;

    // ---- conv1 projections + fused edge phase (2 edges/wave) ----
    if (tier >= 1) {
        // k|v interleaved into kbuf (row stride 384)
        proj_tiled_kernel<23, 23, 192, 2, 8, true><<<gproj32, 384, 0, stream>>>(
            h1, n, k1w, k1b, kbuf, v1w, v1b, npw, np, np, npw, np, np, npw);
        if (tier == 2) {
            // s -> o1, q -> q1buf
            proj_tiled_kernel<23, 23, 192, 2, 8, false><<<gproj32, 384, 0, stream>>>(
                h1, n, s1w, s1b, o1, q1w, q1b, q1buf, np, np, npw, np, np, npw);
            conv_fused_kernel<23, 24, 32, true, true, true><<<CB, 256, 0, stream>>>(
                h1, q1w, q1b, v1w, v1b, kbuf, q1buf, ea, e1w, rp, seS, o1, n, sc1, chunk);
        } else {
            proj_tiled_kernel<23, 23, 192, 1, 8, false><<<gproj32, 192, 0, stream>>>(
                h1, n, s1w, s1b, o1, np, np, npw, np, np, npw, np, np, npw);
            conv_fused_kernel<23, 24, 32, true, false, true><<<CB, 256, 0, stream>>>(
                h1, q1w, q1b, v1w, v1b, kbuf, np, ea, e1w, rp, seS, o1, n, sc1, chunk);
        }
    } else {
        // k -> kbuf (stride 192), s -> o1
        proj_tiled_kernel<23, 23, 192, 2, 8, false><<<gproj32, 384, 0, stream>>>(
            h1, n, k1w, k1b, kbuf, s1w, s1b, o1, np, np, npw, np, np, npw);
        conv_fused_kernel<23, 24, 64, false, false, true><<<CB, 256, 0, stream>>>(
            h1, q1w, q1b, v1w, v1b, kbuf, np, ea, e1w, rp, seS, o1, n, sc1, chunk);
    }

    // ---- conv2 projections + fused edge phase (4 edges/wave) ----
    // k|v interleaved into kv2 (row stride 128)
    proj_tiled_kernel<192, 32, 64, 2, 16, true><<<gproj64, 256, 0, stream>>>(
        o1, n, k2w, k2b, kv2, v2w, v2b, npw, np, np, npw, np, np, npw);
    if (tier >= 1) {
        proj_tiled_kernel<192, 32, 64, 2, 16, false><<<gproj64, 256, 0, stream>>>(
            o1, n, q2w, q2b, q2buf, s2w, s2b, o2, np, np, npw, np, np, npw);
        conv_fused_kernel<192, 8, 16, true, true, false><<<CB, 256, 0, stream>>>(
            o1, q2w, q2b, v2w, v2b, kv2, q2buf, ea, e2w, rp, seS, o2, n, sc2, chunk);
    } else {
        proj_tiled_kernel<192, 32, 64, 1, 16, false><<<gproj64, 128, 0, stream>>>(
            o1, n, s2w, s2b, o2, np, np, npw, np, np, npw, np, np, npw);
        conv_fused_kernel<192, 8, 16, true, false, false><<<CB, 256, 0, stream>>>(
            o1, q2w, q2b, v2w, v2b, kv2, np, ea, e2w, rp, seS, o2, n, sc2, chunk);
    }

    // ---- head ----
    head_kernel<<<(n + B - 1) / B, B, 0, stream>>>(o2, l1w, l1b, l2w, l2b, out, n);
}

// Round 7
// 1159.642 us; speedup vs baseline: 1.2244x; 1.2244x over previous
//
#include <hip/hip_runtime.h>
#include <math.h>

// ---------------- device helpers ----------------

__device__ __forceinline__ float elu_f(float x) {
    return x > 0.f ? x : expm1f(x);
}

// ---------------- node MLP ----------------

__global__ void mlp_kernel(const float* __restrict__ x,
                           const float* __restrict__ A, const float* __restrict__ ab,
                           const float* __restrict__ B, const float* __restrict__ bb,
                           float* __restrict__ out, int n) {
    __shared__ float sA[23 * 23], sB[23 * 23], sa[23], sb[23];
    for (int t = threadIdx.x; t < 23 * 23; t += blockDim.x) { sA[t] = A[t]; sB[t] = B[t]; }
    if (threadIdx.x < 23) { sa[threadIdx.x] = ab[threadIdx.x]; sb[threadIdx.x] = bb[threadIdx.x]; }
    __syncthreads();
    int i = blockIdx.x * blockDim.x + threadIdx.x;
    if (i >= n) return;
    float xi[23], h1[23];
    #pragma unroll
    for (int j = 0; j < 23; j++) xi[j] = x[(size_t)i * 23 + j];
    #pragma unroll
    for (int o = 0; o < 23; o++) {
        float acc = sa[o];
        #pragma unroll
        for (int j = 0; j < 23; j++) acc = fmaf(xi[j], sA[j * 23 + o], acc);
        h1[o] = elu_f(acc);
    }
    #pragma unroll
    for (int o = 0; o < 23; o++) {
        float acc = sb[o];
        #pragma unroll
        for (int j = 0; j < 23; j++) acc = fmaf(h1[j], sB[j * 23 + o], acc);
        out[(size_t)i * 23 + o] = elu_f(acc);
    }
}

// ---------------- register-tiled multi-output projection (GEMM) ----------------
// FUSED=false: each mat m writes its own buffer o_m with row stride OUTW.
// FUSED=true : all mats write one buffer o0 with row stride WTOT at col m*OUTW+cc
//              (interleaved per-node layout, e.g. k|v rows adjacent).
template<int IN, int Kc, int OUTW, int M, int TY, bool FUSED>
__global__ void proj_tiled_kernel(const float* __restrict__ in, int n,
    const float* __restrict__ W0, const float* __restrict__ b0, float* __restrict__ o0,
    const float* __restrict__ W1, const float* __restrict__ b1, float* __restrict__ o1,
    const float* __restrict__ W2, const float* __restrict__ b2, float* __restrict__ o2,
    const float* __restrict__ W3, const float* __restrict__ b3, float* __restrict__ o3) {
    constexpr int WTOT = M * OUTW;
    constexpr int CG   = WTOT / 8;
    constexpr int BN   = TY * 4;
    constexpr int SAW  = BN + 4;
    constexpr int NT   = CG * TY;
    static_assert(IN % Kc == 0, "Kc must divide IN");
    static_assert(WTOT % 8 == 0 && OUTW % 4 == 0, "col alignment");
    __shared__ float sA[Kc][SAW];
    __shared__ float sB[Kc][WTOT];

    const int tid = threadIdx.x;
    const int tx = tid % CG;
    const int ty = tid / CG;
    const int node0 = blockIdx.x * BN;

    const int colA = tx * 4;
    const int colB = WTOT / 2 + tx * 4;
    const int matA = colA / OUTW, ccA = colA % OUTW;
    const int matB = colB / OUTW, ccB = colB % OUTW;
    const float* bA = (matA == 0 ? b0 : matA == 1 ? b1 : matA == 2 ? b2 : b3);
    const float* bB = (matB == 0 ? b0 : matB == 1 ? b1 : matB == 2 ? b2 : b3);
    float*       oA = (matA == 0 ? o0 : matA == 1 ? o1 : matA == 2 ? o2 : o3);
    float*       oB = (matB == 0 ? o0 : matB == 1 ? o1 : matB == 2 ? o2 : o3);

    float acc[4][8];
    #pragma unroll
    for (int i = 0; i < 4; i++) {
        #pragma unroll
        for (int c = 0; c < 4; c++) { acc[i][c] = bA[ccA + c]; acc[i][4 + c] = bB[ccB + c]; }
    }

    for (int k0 = 0; k0 < IN; k0 += Kc) {
        for (int t = tid; t < Kc * BN; t += NT) {
            int j = t / BN, nn = t - j * BN;
            int g = node0 + nn;
            sA[j][nn] = (g < n) ? in[(size_t)g * IN + k0 + j] : 0.f;
        }
        for (int t = tid; t < Kc * WTOT; t += NT) {
            int j = t / WTOT, c = t - j * WTOT;
            int m = c / OUTW, cm = c - m * OUTW;
            const float* Wp = (m == 0 ? W0 : m == 1 ? W1 : m == 2 ? W2 : W3);
            sB[j][c] = Wp[(size_t)(k0 + j) * OUTW + cm];
        }
        __syncthreads();
        #pragma unroll 8
        for (int j = 0; j < Kc; j++) {
            float4 a  = *(const float4*)&sA[j][ty * 4];
            float4 v0 = *(const float4*)&sB[j][colA];
            float4 v1 = *(const float4*)&sB[j][colB];
            float av[4] = {a.x, a.y, a.z, a.w};
            float bv[8] = {v0.x, v0.y, v0.z, v0.w, v1.x, v1.y, v1.z, v1.w};
            #pragma unroll
            for (int i = 0; i < 4; i++)
                #pragma unroll
                for (int c = 0; c < 8; c++)
                    acc[i][c] = fmaf(av[i], bv[c], acc[i][c]);
        }
        __syncthreads();
    }

    #pragma unroll
    for (int i = 0; i < 4; i++) {
        int g = node0 + ty * 4 + i;
        if (g >= n) continue;
        if constexpr (FUSED) {
            *(float4*)(o0 + (size_t)g * WTOT + colA) = make_float4(acc[i][0], acc[i][1], acc[i][2], acc[i][3]);
            *(float4*)(o0 + (size_t)g * WTOT + colB) = make_float4(acc[i][4], acc[i][5], acc[i][6], acc[i][7]);
        } else {
            *(float4*)(oA + (size_t)g * OUTW + ccA) = make_float4(acc[i][0], acc[i][1], acc[i][2], acc[i][3]);
            *(float4*)(oB + (size_t)g * OUTW + ccB) = make_float4(acc[i][4], acc[i][5], acc[i][6], acc[i][7]);
        }
    }
}

// ---------------- CSR build ----------------

__global__ void zero2_kernel(int* __restrict__ a, int* __restrict__ b, int n) {
    int i = blockIdx.x * blockDim.x + threadIdx.x;
    if (i < n) { a[i] = 0; b[i] = 0; }
}

__global__ void count_kernel(const int* __restrict__ dst, int* __restrict__ cnt, int nE) {
    int e = blockIdx.x * blockDim.x + threadIdx.x;
    if (e < nE) atomicAdd(&cnt[dst[e]], 1);
}

__global__ void scan_block_kernel(int* __restrict__ cnt, int* __restrict__ bsum, int n) {
    __shared__ int sdat[256];
    int i = blockIdx.x * 256 + threadIdx.x;
    int v = (i < n) ? cnt[i] : 0;
    sdat[threadIdx.x] = v;
    __syncthreads();
    for (int off = 1; off < 256; off <<= 1) {
        int t = (threadIdx.x >= (unsigned)off) ? sdat[threadIdx.x - off] : 0;
        __syncthreads();
        sdat[threadIdx.x] += t;
        __syncthreads();
    }
    if (i < n) cnt[i] = sdat[threadIdx.x] - v;
    if (threadIdx.x == 255) bsum[blockIdx.x] = sdat[255];
}

__global__ void scan_bsum_kernel(int* __restrict__ bsum, int nb) {
    __shared__ int s[1024];
    int i = threadIdx.x;
    int v = (i < nb) ? bsum[i] : 0;
    s[i] = v;
    __syncthreads();
    for (int off = 1; off < 1024; off <<= 1) {
        int t = (i >= off) ? s[i - off] : 0;
        __syncthreads();
        s[i] += t;
        __syncthreads();
    }
    if (i < nb) bsum[i] = s[i] - v;
}

__global__ void finalize_rp_kernel(const int* __restrict__ cnt, const int* __restrict__ bsum,
                                   int* __restrict__ rp, int n, int nE) {
    int i = blockIdx.x * blockDim.x + threadIdx.x;
    if (i < n) rp[i] = cnt[i] + bsum[i >> 8];
    if (i == n) rp[n] = nE;
}

__global__ void scatter_kernel(const int* __restrict__ src, const int* __restrict__ dst,
                               const int* __restrict__ rp, int* __restrict__ cur,
                               int2* __restrict__ seS, int nE) {
    int e = blockIdx.x * blockDim.x + threadIdx.x;
    if (e >= nE) return;
    int d = dst[e];
    int pos = rp[d] + atomicAdd(&cur[d], 1);
    seS[pos] = make_int2(src[e], e);
}

// ---------------- fused TransformerConv ----------------
// R0 structure (proven 408us/52VGPR/no-spill) + NPW nodes per wave:
// the wave's 64 lanes are split into NPW sub-groups of LSPL=64/NPW lanes,
// each owning ONE dst node with an independent online-softmax state.
// No stream merge, no shadow registers (rounds 2-6: every register-level
// prefetch/pipeline variant spilled at the 64-VGPR allocator target).
// Per iteration the wave issues NPW independent kv-row gathers -> NPWx MLP.
// Predication handles degree imbalance: rs=(m==mn)?1:expf(m-mn) guards the
// -inf start; pw=act?..:0 zeroes dead contributions. Math order per node is
// IDENTICAL to the baseline serial loop.
// WELDS: We table in LDS (saves 7*CPL VGPRs; used by the NPW=4 conv2 build).
// VMAT layout: interleaved kv rows, row stride 2*HC, v at offset +HC.
template<int IN, int C, int NPW, bool VMAT, bool QMAT, bool WELDS, bool DOELU>
__global__ void conv_fused_kernel(const float* __restrict__ feat,
                                  const float* __restrict__ Wq, const float* __restrict__ qb,
                                  const float* __restrict__ Wv, const float* __restrict__ vb,
                                  const float* __restrict__ kmat, const float* __restrict__ qmat,
                                  const float* __restrict__ ea, const float* __restrict__ We,
                                  const int* __restrict__ rp, const int2* __restrict__ seS,
                                  float* __restrict__ out, int n, float scale) {
    constexpr int HC   = 8 * C;
    constexpr int LSPL = 64 / NPW;      // lanes per node
    constexpr int CPL  = HC / LSPL;     // channels per lane
    constexpr int LPG  = C / CPL;       // lanes per head (shfl reduce width)
    static_assert(HC % LSPL == 0 && C % CPL == 0, "split alignment");

    __shared__ float sWe[WELDS ? 7 * HC : 1];
    __shared__ float sWv[VMAT ? 1 : IN * HC];
    if constexpr (WELDS) {
        for (int t = threadIdx.x; t < 7 * HC; t += blockDim.x) sWe[t] = We[t];
    }
    if constexpr (!VMAT) {
        for (int t = threadIdx.x; t < IN * HC; t += blockDim.x) sWv[t] = Wv[t];
    }
    if constexpr (WELDS || !VMAT) __syncthreads();

    const int lane = threadIdx.x & 63;
    const int wv = (blockIdx.x * blockDim.x + threadIdx.x) >> 6;
    const int sub = lane / LSPL;
    const int li  = lane % LSPL;
    const int ch0 = li * CPL;
    const int d = wv * NPW + sub;
    const bool dv = (d < n);
    if (!__any(dv ? 1 : 0)) return;

    float we[7][CPL];
    if constexpr (!WELDS) {
        #pragma unroll
        for (int j = 0; j < 7; j++)
            #pragma unroll
            for (int c = 0; c < CPL; c++) we[j][c] = We[j * HC + ch0 + c];
    }

    float vbr[CPL];
    if constexpr (!VMAT) {
        #pragma unroll
        for (int c = 0; c < CPL; c++) vbr[c] = vb[ch0 + c];
    }

    // q for this node
    float q[CPL];
    if (dv) {
        if constexpr (QMAT) {
            const float* qp = qmat + (size_t)d * HC + ch0;
            #pragma unroll
            for (int c = 0; c < CPL; c++) q[c] = qp[c];
        } else {
            #pragma unroll
            for (int c = 0; c < CPL; c++) q[c] = qb[ch0 + c];
            const float* fd = feat + (size_t)d * IN;
            for (int j = 0; j < IN; j++) {
                float f = fd[j];
                #pragma unroll
                for (int c = 0; c < CPL; c++)
                    q[c] = fmaf(f, Wq[(size_t)j * HC + ch0 + c], q[c]);
            }
        }
    } else {
        #pragma unroll
        for (int c = 0; c < CPL; c++) q[c] = 0.f;
    }

    float m = -INFINITY, l = 0.f, acc[CPL];
    #pragma unroll
    for (int c = 0; c < CPL; c++) acc[c] = 0.f;

    int p   = dv ? rp[d] : 0;
    int pEv = dv ? rp[d + 1] : 0;

    for (;;) {
        bool act = (p < pEv);
        if (!__any(act ? 1 : 0)) break;

        float kc[CPL], vc[CPL], ec[7];
        if (act) {
            int2 se = seS[p];
            const float* ep = ea + (size_t)se.y * 7;
            #pragma unroll
            for (int j = 0; j < 7; j++) ec[j] = ep[j];
            if constexpr (VMAT) {
                const float* kp = kmat + (size_t)se.x * (2 * HC) + ch0;
                #pragma unroll
                for (int c = 0; c < CPL; c++) kc[c] = kp[c];
                #pragma unroll
                for (int c = 0; c < CPL; c++) vc[c] = kp[HC + c];
            } else {
                const float* kp = kmat + (size_t)se.x * HC + ch0;
                #pragma unroll
                for (int c = 0; c < CPL; c++) kc[c] = kp[c];
                #pragma unroll
                for (int c = 0; c < CPL; c++) vc[c] = vbr[c];
                const float* fs = feat + (size_t)se.x * IN;
                for (int j = 0; j < IN; j++) {
                    float f = fs[j];
                    #pragma unroll
                    for (int c = 0; c < CPL; c++) vc[c] = fmaf(f, sWv[j * HC + ch0 + c], vc[c]);
                }
            }
        } else {
            #pragma unroll
            for (int j = 0; j < 7; j++) ec[j] = 0.f;
            #pragma unroll
            for (int c = 0; c < CPL; c++) { kc[c] = 0.f; vc[c] = 0.f; }
        }

        float part = 0.f, tv[CPL];
        #pragma unroll
        for (int c = 0; c < CPL; c++) {
            float t = 0.f;
            if constexpr (WELDS) {
                #pragma unroll
                for (int j = 0; j < 7; j++) t = fmaf(ec[j], sWe[j * HC + ch0 + c], t);
            } else {
                #pragma unroll
                for (int j = 0; j < 7; j++) t = fmaf(ec[j], we[j][c], t);
            }
            tv[c] = t;
            part = fmaf(q[c], kc[c] + t, part);
        }
        if constexpr (LPG > 1) part += __shfl_xor(part, 1);
        if constexpr (LPG > 2) part += __shfl_xor(part, 2);
        if constexpr (LPG > 4) part += __shfl_xor(part, 4);
        float z = part * scale;
        float mn = act ? fmaxf(m, z) : m;
        float rs = (m == mn) ? 1.f : expf(m - mn);   // ==: exact 1 (also guards -inf)
        float pw = act ? expf(z - mn) : 0.f;
        l = l * rs + pw;
        #pragma unroll
        for (int c = 0; c < CPL; c++) acc[c] = fmaf(acc[c], rs, pw * (vc[c] + tv[c]));
        m = mn;
        p++;
    }

    // output: skip row read late, add normalized aggregate
    if (dv) {
        float invl = (l > 0.f) ? 1.f / l : 0.f;
        float* op = out + (size_t)d * HC + ch0;
        #pragma unroll
        for (int c = 0; c < CPL; c++) {
            float r = op[c] + acc[c] * invl;
            op[c] = DOELU ? elu_f(r) : r;
        }
    }
}

// ---------------- head ----------------
__global__ void head_kernel(const float* __restrict__ h, const float* __restrict__ W1,
                            const float* __restrict__ b1, const float* __restrict__ W2,
                            const float* __restrict__ b2, float* __restrict__ out, int n) {
    __shared__ float sW1[64 * 20], sb1[20], sW2[20], sb2;
    for (int t = threadIdx.x; t < 64 * 20; t += blockDim.x) sW1[t] = W1[t];
    if (threadIdx.x < 20) { sb1[threadIdx.x] = b1[threadIdx.x]; sW2[threadIdx.x] = W2[threadIdx.x]; }
    if (threadIdx.x == 0) sb2 = b2[0];
    __syncthreads();
    int i = blockIdx.x * blockDim.x + threadIdx.x;
    if (i >= n) return;
    float hv[64];
    const float* hp = h + (size_t)i * 64;
    #pragma unroll
    for (int j = 0; j < 64; j++) hv[j] = elu_f(hp[j]);
    float acc2 = sb2;
    for (int o = 0; o < 20; o++) {
        float a = sb1[o];
        #pragma unroll
        for (int j = 0; j < 64; j++) a = fmaf(hv[j], sW1[j * 20 + o], a);
        acc2 = fmaf(elu_f(a), sW2[o], acc2);
    }
    out[i] = acc2;
}

__global__ void zero_out_kernel(float* __restrict__ out, int n) {
    int i = blockIdx.x * blockDim.x + threadIdx.x;
    if (i < n) out[i] = 0.f;
}

// ---------------- launcher ----------------

extern "C" void kernel_launch(void* const* d_in, const int* in_sizes, int n_in,
                              void* d_out, int out_size, void* d_ws, size_t ws_size,
                              hipStream_t stream) {
    const float* x   = (const float*)d_in[0];
    const int*   ei  = (const int*)d_in[1];
    const float* ea  = (const float*)d_in[2];
    const float* Aw  = (const float*)d_in[3];
    const float* Ab  = (const float*)d_in[4];
    const float* Bw  = (const float*)d_in[5];
    const float* Bb  = (const float*)d_in[6];
    const float* q1w = (const float*)d_in[7];  const float* q1b = (const float*)d_in[8];
    const float* k1w = (const float*)d_in[9];  const float* k1b = (const float*)d_in[10];
    const float* v1w = (const float*)d_in[11]; const float* v1b = (const float*)d_in[12];
    const float* e1w = (const float*)d_in[13];
    const float* s1w = (const float*)d_in[14]; const float* s1b = (const float*)d_in[15];
    const float* q2w = (const float*)d_in[16]; const float* q2b = (const float*)d_in[17];
    const float* k2w = (const float*)d_in[18]; const float* k2b = (const float*)d_in[19];
    const float* v2w = (const float*)d_in[20]; const float* v2b = (const float*)d_in[21];
    const float* e2w = (const float*)d_in[22];
    const float* s2w = (const float*)d_in[23]; const float* s2b = (const float*)d_in[24];
    const float* l1w = (const float*)d_in[25]; const float* l1b = (const float*)d_in[26];
    const float* l2w = (const float*)d_in[27]; const float* l2b = (const float*)d_in[28];

    const int n  = in_sizes[0] / 23;
    const int nE = in_sizes[1] / 2;
    const int* src = ei;
    const int* dst = ei + nE;
    float* out = (float*)d_out;
    const int B = 256;
    const int nb = (n + 255) / 256;

    // ---- workspace layout ----
    size_t fl_h1 = ((size_t)n * 23 + 3) & ~(size_t)3;
    size_t fl_o1 = (size_t)n * 192;
    size_t fl_kvA = (size_t)n * 384;   // tierA+: kv1 interleaved, later kv2|q2|o2
    size_t fl_kB  = (size_t)n * 192;   // tierB: k1, later kv2|o2
    size_t fl_q1  = (size_t)n * 192;   // tierA2 only: q1 projection
    size_t ints_total = 2 * (size_t)nE + ((size_t)n + 1) + n + n + 1024;

    size_t tierB_bytes  = (fl_h1 + fl_o1 + fl_kB) * 4 + ints_total * 4;
    size_t tierA_bytes  = (fl_h1 + fl_o1 + fl_kvA) * 4 + ints_total * 4;
    size_t tierA2_bytes = tierA_bytes + fl_q1 * 4;

    if (ws_size < tierB_bytes || nb > 1024) {
        zero_out_kernel<<<(out_size + B - 1) / B, B, 0, stream>>>(out, out_size);
        return;
    }
    const int tier = (ws_size >= tierA2_bytes) ? 2 : (ws_size >= tierA_bytes) ? 1 : 0;

    float* ws = (float*)d_ws;
    size_t off = 0;
    float* h1   = ws + off; off += fl_h1;
    float* o1   = ws + off; off += fl_o1;
    float* kbuf = ws + off; off += (tier >= 1 ? fl_kvA : fl_kB);
    float* q1buf = nullptr;
    if (tier == 2) { q1buf = ws + off; off += fl_q1; }
    // int area: seS first (8B-aligned since all float counts above are even)
    int2* seS = (int2*)(ws + off);
    int* ip = (int*)(seS + nE);
    int* rp   = ip; ip += (size_t)n + 1;
    int* cnt  = ip; ip += n;
    int* cur  = ip; ip += n;
    int* bsum = ip;

    // conv1: kv1 = kbuf (interleaved n x 384) for tier>=1; k-only (n x 192) tier0
    // conv2 buffers alias kbuf region (conv1 edge phase completes first):
    float* kv2   = kbuf;                                        // n x 128 interleaved
    float* q2buf = (tier >= 1) ? (kbuf + (size_t)n * 128) : nullptr;  // n x 64
    float* o2    = (tier >= 1) ? (kbuf + (size_t)n * 192) : (kbuf + (size_t)n * 128); // n x 64

    const float sc1 = 1.0f / sqrtf(24.0f);
    const float sc2 = 1.0f / sqrtf(8.0f);
    const float* np = nullptr;
    float* npw = nullptr;

    // ---- CSR build ----
    zero2_kernel<<<(n + B - 1) / B, B, 0, stream>>>(cnt, cur, n);
    count_kernel<<<(nE + B - 1) / B, B, 0, stream>>>(dst, cnt, nE);
    scan_block_kernel<<<nb, 256, 0, stream>>>(cnt, bsum, n);
    scan_bsum_kernel<<<1, 1024, 0, stream>>>(bsum, nb);
    finalize_rp_kernel<<<(n + 1 + B - 1) / B, B, 0, stream>>>(cnt, bsum, rp, n, nE);
    scatter_kernel<<<(nE + B - 1) / B, B, 0, stream>>>(src, dst, rp, cur, seS, nE);

    // ---- node MLP ----
    mlp_kernel<<<(n + B - 1) / B, B, 0, stream>>>(x, Aw, Ab, Bw, Bb, h1, n);

    const int gproj32 = (n + 31) / 32;
    const int gproj64 = (n + 63) / 64;

    // conv grids: R0-style direct mapping.
    // conv1: 1 node/wave, 4 waves/block; conv2: 4 nodes/wave, 4 waves/block
    const int cb1 = (n + 3) / 4;
    const int cb2 = (n + 15) / 16;

    // ---- conv1 projections + fused edge phase ----
    if (tier >= 1) {
        // k|v interleaved into kbuf (row stride 384)
        proj_tiled_kernel<23, 23, 192, 2, 8, true><<<gproj32, 384, 0, stream>>>(
            h1, n, k1w, k1b, kbuf, v1w, v1b, npw, np, np, npw, np, np, npw);
        if (tier == 2) {
            // s -> o1, q -> q1buf
            proj_tiled_kernel<23, 23, 192, 2, 8, false><<<gproj32, 384, 0, stream>>>(
                h1, n, s1w, s1b, o1, q1w, q1b, q1buf, np, np, npw, np, np, npw);
            conv_fused_kernel<23, 24, 1, true, true, false, true><<<cb1, 256, 0, stream>>>(
                h1, q1w, q1b, v1w, v1b, kbuf, q1buf, ea, e1w, rp, seS, o1, n, sc1);
        } else {
            proj_tiled_kernel<23, 23, 192, 1, 8, false><<<gproj32, 192, 0, stream>>>(
                h1, n, s1w, s1b, o1, np, np, npw, np, np, npw, np, np, npw);
            conv_fused_kernel<23, 24, 1, true, false, false, true><<<cb1, 256, 0, stream>>>(
                h1, q1w, q1b, v1w, v1b, kbuf, np, ea, e1w, rp, seS, o1, n, sc1);
        }
    } else {
        // k -> kbuf (stride 192), s -> o1
        proj_tiled_kernel<23, 23, 192, 2, 8, false><<<gproj32, 384, 0, stream>>>(
            h1, n, k1w, k1b, kbuf, s1w, s1b, o1, np, np, npw, np, np, npw);
        conv_fused_kernel<23, 24, 1, false, false, false, true><<<cb1, 256, 0, stream>>>(
            h1, q1w, q1b, v1w, v1b, kbuf, np, ea, e1w, rp, seS, o1, n, sc1);
    }

    // ---- conv2 projections + fused edge phase (4 nodes/wave) ----
    // k|v interleaved into kv2 (row stride 128)
    proj_tiled_kernel<192, 32, 64, 2, 16, true><<<gproj64, 256, 0, stream>>>(
        o1, n, k2w, k2b, kv2, v2w, v2b, npw, np, np, npw, np, np, npw);
    if (tier >= 1) {
        proj_tiled_kernel<192, 32, 64, 2, 16, false><<<gproj64, 256, 0, stream>>>(
            o1, n, q2w, q2b, q2buf, s2w, s2b, o2, np, np, npw, np, np, npw);
        conv_fused_kernel<192, 8, 4, true, true, true, false><<<cb2, 256, 0, stream>>>(
            o1, q2w, q2b, v2w, v2b, kv2, q2buf, ea, e2w, rp, seS, o2, n, sc2);
    } else {
        proj_tiled_kernel<192, 32, 64, 1, 16, false><<<gproj64, 128, 0, stream>>>(
            o1, n, s2w, s2b, o2, np, np, npw, np, np, npw, np, np, npw);
        conv_fused_kernel<192, 8, 4, true, false, true, false><<<cb2, 256, 0, stream>>>(
            o1, q2w, q2b, v2w, v2b, kv2, np, ea, e2w, rp, seS, o2, n, sc2);
    }

    // ---- head ----
    head_kernel<<<(n + B - 1) / B, B, 0, stream>>>(o2, l1w, l1b, l2w, l2b, out, n);
}

// Round 8
// 1109.719 us; speedup vs baseline: 1.2795x; 1.0450x over previous
//
#include <hip/hip_runtime.h>
#include <math.h>

// ---------------- device helpers ----------------

__device__ __forceinline__ float elu_f(float x) {
    return x > 0.f ? x : expm1f(x);
}

// ---------------- node MLP ----------------

__global__ void mlp_kernel(const float* __restrict__ x,
                           const float* __restrict__ A, const float* __restrict__ ab,
                           const float* __restrict__ B, const float* __restrict__ bb,
                           float* __restrict__ out, int n) {
    __shared__ float sA[23 * 23], sB[23 * 23], sa[23], sb[23];
    for (int t = threadIdx.x; t < 23 * 23; t += blockDim.x) { sA[t] = A[t]; sB[t] = B[t]; }
    if (threadIdx.x < 23) { sa[threadIdx.x] = ab[threadIdx.x]; sb[threadIdx.x] = bb[threadIdx.x]; }
    __syncthreads();
    int i = blockIdx.x * blockDim.x + threadIdx.x;
    if (i >= n) return;
    float xi[23], h1[23];
    #pragma unroll
    for (int j = 0; j < 23; j++) xi[j] = x[(size_t)i * 23 + j];
    #pragma unroll
    for (int o = 0; o < 23; o++) {
        float acc = sa[o];
        #pragma unroll
        for (int j = 0; j < 23; j++) acc = fmaf(xi[j], sA[j * 23 + o], acc);
        h1[o] = elu_f(acc);
    }
    #pragma unroll
    for (int o = 0; o < 23; o++) {
        float acc = sb[o];
        #pragma unroll
        for (int j = 0; j < 23; j++) acc = fmaf(h1[j], sB[j * 23 + o], acc);
        out[(size_t)i * 23 + o] = elu_f(acc);
    }
}

// ---------------- register-tiled multi-output projection (GEMM) ----------------
template<int IN, int Kc, int OUTW, int M, int TY>
__global__ void proj_tiled_kernel(const float* __restrict__ in, int n,
    const float* __restrict__ W0, const float* __restrict__ b0, float* __restrict__ o0,
    const float* __restrict__ W1, const float* __restrict__ b1, float* __restrict__ o1,
    const float* __restrict__ W2, const float* __restrict__ b2, float* __restrict__ o2,
    const float* __restrict__ W3, const float* __restrict__ b3, float* __restrict__ o3) {
    constexpr int WTOT = M * OUTW;
    constexpr int CG   = WTOT / 8;
    constexpr int BN   = TY * 4;
    constexpr int SAW  = BN + 4;
    constexpr int NT   = CG * TY;
    static_assert(IN % Kc == 0, "Kc must divide IN");
    static_assert(WTOT % 8 == 0 && OUTW % 4 == 0, "col alignment");
    __shared__ float sA[Kc][SAW];
    __shared__ float sB[Kc][WTOT];

    const int tid = threadIdx.x;
    const int tx = tid % CG;
    const int ty = tid / CG;
    const int node0 = blockIdx.x * BN;

    const int colA = tx * 4;
    const int colB = WTOT / 2 + tx * 4;
    const int matA = colA / OUTW, ccA = colA % OUTW;
    const int matB = colB / OUTW, ccB = colB % OUTW;
    const float* bA = (matA == 0 ? b0 : matA == 1 ? b1 : matA == 2 ? b2 : b3);
    const float* bB = (matB == 0 ? b0 : matB == 1 ? b1 : matB == 2 ? b2 : b3);
    float*       oA = (matA == 0 ? o0 : matA == 1 ? o1 : matA == 2 ? o2 : o3);
    float*       oB = (matB == 0 ? o0 : matB == 1 ? o1 : matB == 2 ? o2 : o3);

    float acc[4][8];
    #pragma unroll
    for (int i = 0; i < 4; i++) {
        #pragma unroll
        for (int c = 0; c < 4; c++) { acc[i][c] = bA[ccA + c]; acc[i][4 + c] = bB[ccB + c]; }
    }

    for (int k0 = 0; k0 < IN; k0 += Kc) {
        for (int t = tid; t < Kc * BN; t += NT) {
            int j = t / BN, nn = t - j * BN;
            int g = node0 + nn;
            sA[j][nn] = (g < n) ? in[(size_t)g * IN + k0 + j] : 0.f;
        }
        for (int t = tid; t < Kc * WTOT; t += NT) {
            int j = t / WTOT, c = t - j * WTOT;
            int m = c / OUTW, cm = c - m * OUTW;
            const float* Wp = (m == 0 ? W0 : m == 1 ? W1 : m == 2 ? W2 : W3);
            sB[j][c] = Wp[(size_t)(k0 + j) * OUTW + cm];
        }
        __syncthreads();
        #pragma unroll 8
        for (int j = 0; j < Kc; j++) {
            float4 a  = *(const float4*)&sA[j][ty * 4];
            float4 v0 = *(const float4*)&sB[j][colA];
            float4 v1 = *(const float4*)&sB[j][colB];
            float av[4] = {a.x, a.y, a.z, a.w};
            float bv[8] = {v0.x, v0.y, v0.z, v0.w, v1.x, v1.y, v1.z, v1.w};
            #pragma unroll
            for (int i = 0; i < 4; i++)
                #pragma unroll
                for (int c = 0; c < 8; c++)
                    acc[i][c] = fmaf(av[i], bv[c], acc[i][c]);
        }
        __syncthreads();
    }

    #pragma unroll
    for (int i = 0; i < 4; i++) {
        int g = node0 + ty * 4 + i;
        if (g >= n) continue;
        *(float4*)(oA + (size_t)g * OUTW + ccA) = make_float4(acc[i][0], acc[i][1], acc[i][2], acc[i][3]);
        *(float4*)(oB + (size_t)g * OUTW + ccB) = make_float4(acc[i][4], acc[i][5], acc[i][6], acc[i][7]);
    }
}

// ---------------- CSR build ----------------

__global__ void zero2_kernel(int* __restrict__ a, int* __restrict__ b, int n) {
    int i = blockIdx.x * blockDim.x + threadIdx.x;
    if (i < n) { a[i] = 0; b[i] = 0; }
}

__global__ void count_kernel(const int* __restrict__ dst, int* __restrict__ cnt, int nE) {
    int e = blockIdx.x * blockDim.x + threadIdx.x;
    if (e < nE) atomicAdd(&cnt[dst[e]], 1);
}

__global__ void scan_block_kernel(int* __restrict__ cnt, int* __restrict__ bsum, int n) {
    __shared__ int sdat[256];
    int i = blockIdx.x * 256 + threadIdx.x;
    int v = (i < n) ? cnt[i] : 0;
    sdat[threadIdx.x] = v;
    __syncthreads();
    for (int off = 1; off < 256; off <<= 1) {
        int t = (threadIdx.x >= (unsigned)off) ? sdat[threadIdx.x - off] : 0;
        __syncthreads();
        sdat[threadIdx.x] += t;
        __syncthreads();
    }
    if (i < n) cnt[i] = sdat[threadIdx.x] - v;
    if (threadIdx.x == 255) bsum[blockIdx.x] = sdat[255];
}

__global__ void scan_bsum_kernel(int* __restrict__ bsum, int nb) {
    __shared__ int s[1024];
    int i = threadIdx.x;
    int v = (i < nb) ? bsum[i] : 0;
    s[i] = v;
    __syncthreads();
    for (int off = 1; off < 1024; off <<= 1) {
        int t = (i >= off) ? s[i - off] : 0;
        __syncthreads();
        s[i] += t;
        __syncthreads();
    }
    if (i < nb) bsum[i] = s[i] - v;
}

__global__ void finalize_rp_kernel(const int* __restrict__ cnt, const int* __restrict__ bsum,
                                   int* __restrict__ rp, int n, int nE) {
    int i = blockIdx.x * blockDim.x + threadIdx.x;
    if (i < n) rp[i] = cnt[i] + bsum[i >> 8];
    if (i == n) rp[n] = nE;
}

__global__ void scatter_kernel(const int* __restrict__ src, const int* __restrict__ dst,
                               const int* __restrict__ rp, int* __restrict__ cur,
                               int* __restrict__ srcS, int* __restrict__ eidS, int nE) {
    int e = blockIdx.x * blockDim.x + threadIdx.x;
    if (e >= nE) return;
    int d = dst[e];
    int pos = rp[d] + atomicAdd(&cur[d], 1);
    srcS[pos] = src[e];
    eidS[pos] = e;
}

// ---------------- fused TransformerConv (one wave per dst node) ----------------
// EXACT R0 structure: the only verified no-spill configuration (52 VGPR,
// WRITE_SIZE 75 MB, conv1 408us). Rounds 2-7: every structural deviation
// (register prefetch, launch_bounds, lane/node-split, predicated loop,
// merged int2 stream) tripped scratch spilling at the allocator's 64-VGPR
// occupancy target and regressed. Do not restructure this loop.
template<int IN, int C, bool VMAT, bool QMAT, bool DOELU>
__global__ void conv_fused_kernel(const float* __restrict__ feat,
                                  const float* __restrict__ Wq, const float* __restrict__ qb,
                                  const float* __restrict__ Wv, const float* __restrict__ vb,
                                  const float* __restrict__ kmat, const float* __restrict__ vmat,
                                  const float* __restrict__ qmat,
                                  const float* __restrict__ ea, const float* __restrict__ We,
                                  const int* __restrict__ rp, const int* __restrict__ srcS,
                                  const int* __restrict__ eidS,
                                  float* __restrict__ out, int n, float scale) {
    constexpr int HC = 8 * C;
    constexpr int CPL = HC / 64;
    __shared__ float sWv[VMAT ? 1 : IN * HC];
    if constexpr (!VMAT) {
        for (int t = threadIdx.x; t < IN * HC; t += blockDim.x) sWv[t] = Wv[t];
        __syncthreads();
    }
    const int lane = threadIdx.x & 63;
    const int d = blockIdx.x * (blockDim.x >> 6) + (threadIdx.x >> 6);
    if (d >= n) return;
    const int ch0 = lane * CPL;

    float we[7][CPL];
    #pragma unroll
    for (int j = 0; j < 7; j++)
        #pragma unroll
        for (int c = 0; c < CPL; c++) we[j][c] = We[j * HC + ch0 + c];

    float vbr[CPL];
    if constexpr (!VMAT) {
        #pragma unroll
        for (int c = 0; c < CPL; c++) vbr[c] = vb[ch0 + c];
    }

    float* op = out + (size_t)d * HC + ch0;
    float sk[CPL], q[CPL];
    #pragma unroll
    for (int c = 0; c < CPL; c++) sk[c] = op[c];   // pre-stored skip projection
    if constexpr (QMAT) {
        const float* qp = qmat + (size_t)d * HC + ch0;
        #pragma unroll
        for (int c = 0; c < CPL; c++) q[c] = qp[c];
    } else {
        #pragma unroll
        for (int c = 0; c < CPL; c++) q[c] = qb[ch0 + c];
        const float* fd = feat + (size_t)d * IN;
        for (int j = 0; j < IN; j++) {
            float f = fd[j];
            #pragma unroll
            for (int c = 0; c < CPL; c++)
                q[c] = fmaf(f, Wq[(size_t)j * HC + ch0 + c], q[c]);
        }
    }

    float m = -INFINITY, l = 0.f, acc[CPL];
    #pragma unroll
    for (int c = 0; c < CPL; c++) acc[c] = 0.f;

    const int p0 = rp[d], p1 = rp[d + 1];
    for (int p = p0; p < p1; p++) {
        int s = srcS[p];
        int eid = eidS[p];
        const float* eav = ea + (size_t)eid * 7;
        float ev[7];
        #pragma unroll
        for (int j = 0; j < 7; j++) ev[j] = eav[j];

        const float* kp = kmat + (size_t)s * HC + ch0;
        float vv[CPL];
        float part = 0.f;
        #pragma unroll
        for (int c = 0; c < CPL; c++) {
            float ec = 0.f;
            #pragma unroll
            for (int j = 0; j < 7; j++) ec = fmaf(ev[j], we[j][c], ec);
            part = fmaf(q[c], kp[c] + ec, part);
            vv[c] = ec;
        }
        if constexpr (VMAT) {
            const float* vp = vmat + (size_t)s * HC + ch0;
            #pragma unroll
            for (int c = 0; c < CPL; c++) vv[c] += vp[c];
        } else {
            #pragma unroll
            for (int c = 0; c < CPL; c++) vv[c] += vbr[c];
            const float* fs = feat + (size_t)s * IN;
            for (int j = 0; j < IN; j++) {
                float f = fs[j];
                #pragma unroll
                for (int c = 0; c < CPL; c++) vv[c] = fmaf(f, sWv[j * HC + ch0 + c], vv[c]);
            }
        }
        part += __shfl_xor(part, 1);
        part += __shfl_xor(part, 2);
        part += __shfl_xor(part, 4);
        float z = part * scale;
        float mn = fmaxf(m, z);
        float rs = expf(m - mn);
        float pw = expf(z - mn);
        l = l * rs + pw;
        #pragma unroll
        for (int c = 0; c < CPL; c++) acc[c] = fmaf(acc[c], rs, pw * vv[c]);
        m = mn;
    }
    float invl = (l > 0.f) ? 1.f / l : 0.f;
    #pragma unroll
    for (int c = 0; c < CPL; c++) {
        float r = sk[c] + acc[c] * invl;
        op[c] = DOELU ? elu_f(r) : r;
    }
}

// ---------------- head ----------------
__global__ void head_kernel(const float* __restrict__ h, const float* __restrict__ W1,
                            const float* __restrict__ b1, const float* __restrict__ W2,
                            const float* __restrict__ b2, float* __restrict__ out, int n) {
    __shared__ float sW1[64 * 20], sb1[20], sW2[20], sb2;
    for (int t = threadIdx.x; t < 64 * 20; t += blockDim.x) sW1[t] = W1[t];
    if (threadIdx.x < 20) { sb1[threadIdx.x] = b1[threadIdx.x]; sW2[threadIdx.x] = W2[threadIdx.x]; }
    if (threadIdx.x == 0) sb2 = b2[0];
    __syncthreads();
    int i = blockIdx.x * blockDim.x + threadIdx.x;
    if (i >= n) return;
    float hv[64];
    const float* hp = h + (size_t)i * 64;
    #pragma unroll
    for (int j = 0; j < 64; j++) hv[j] = elu_f(hp[j]);
    float acc2 = sb2;
    for (int o = 0; o < 20; o++) {
        float a = sb1[o];
        #pragma unroll
        for (int j = 0; j < 64; j++) a = fmaf(hv[j], sW1[j * 20 + o], a);
        acc2 = fmaf(elu_f(a), sW2[o], acc2);
    }
    out[i] = acc2;
}

__global__ void zero_out_kernel(float* __restrict__ out, int n) {
    int i = blockIdx.x * blockDim.x + threadIdx.x;
    if (i < n) out[i] = 0.f;
}

// ---------------- launcher ----------------

extern "C" void kernel_launch(void* const* d_in, const int* in_sizes, int n_in,
                              void* d_out, int out_size, void* d_ws, size_t ws_size,
                              hipStream_t stream) {
    const float* x   = (const float*)d_in[0];
    const int*   ei  = (const int*)d_in[1];
    const float* ea  = (const float*)d_in[2];
    const float* Aw  = (const float*)d_in[3];
    const float* Ab  = (const float*)d_in[4];
    const float* Bw  = (const float*)d_in[5];
    const float* Bb  = (const float*)d_in[6];
    const float* q1w = (const float*)d_in[7];  const float* q1b = (const float*)d_in[8];
    const float* k1w = (const float*)d_in[9];  const float* k1b = (const float*)d_in[10];
    const float* v1w = (const float*)d_in[11]; const float* v1b = (const float*)d_in[12];
    const float* e1w = (const float*)d_in[13];
    const float* s1w = (const float*)d_in[14]; const float* s1b = (const float*)d_in[15];
    const float* q2w = (const float*)d_in[16]; const float* q2b = (const float*)d_in[17];
    const float* k2w = (const float*)d_in[18]; const float* k2b = (const float*)d_in[19];
    const float* v2w = (const float*)d_in[20]; const float* v2b = (const float*)d_in[21];
    const float* e2w = (const float*)d_in[22];
    const float* s2w = (const float*)d_in[23]; const float* s2b = (const float*)d_in[24];
    const float* l1w = (const float*)d_in[25]; const float* l1b = (const float*)d_in[26];
    const float* l2w = (const float*)d_in[27]; const float* l2b = (const float*)d_in[28];

    const int n  = in_sizes[0] / 23;
    const int nE = in_sizes[1] / 2;
    const int* src = ei;
    const int* dst = ei + nE;
    float* out = (float*)d_out;
    const int B = 256;
    const int nb = (n + 255) / 256;

    // ---- workspace layout (R0 tiers + new tier2 = tierA + q1 buffer) ----
    size_t fl_h1 = ((size_t)n * 23 + 3) & ~(size_t)3;
    size_t fl_o1 = (size_t)n * 192;
    size_t fl_kvA = (size_t)n * 384;   // tierA+: k1|v1, later q2|k2|v2|o2
    size_t fl_kB  = (size_t)n * 192;   // tierB: k1, later k2|v2|o2
    size_t fl_q1  = (size_t)n * 192;   // tier2 only: q1 projection
    size_t ints_total = ((size_t)n + 1) + n + n + 1024 + (size_t)nE + (size_t)nE;

    size_t tierB_bytes  = (fl_h1 + fl_o1 + fl_kB) * 4 + ints_total * 4;
    size_t tierA_bytes  = (fl_h1 + fl_o1 + fl_kvA) * 4 + ints_total * 4;
    size_t tier2_bytes  = tierA_bytes + fl_q1 * 4;

    if (ws_size < tierB_bytes || nb > 1024) {
        zero_out_kernel<<<(out_size + B - 1) / B, B, 0, stream>>>(out, out_size);
        return;
    }
    const int tier = (ws_size >= tier2_bytes) ? 2 : (ws_size >= tierA_bytes) ? 1 : 0;

    float* ws = (float*)d_ws;
    size_t off = 0;
    float* h1   = ws + off; off += fl_h1;
    float* o1   = ws + off; off += fl_o1;
    float* kbuf = ws + off; off += (tier >= 1 ? fl_kvA : fl_kB);
    float* vbuf = (tier >= 1) ? (kbuf + (size_t)n * 192) : nullptr;
    float* q1buf = nullptr;
    if (tier == 2) { q1buf = ws + off; off += fl_q1; }
    int* ip = (int*)(ws + off);
    int* rp   = ip; ip += (size_t)n + 1;
    int* cnt  = ip; ip += n;
    int* cur  = ip; ip += n;
    int* bsum = ip; ip += 1024;
    int* srcS = ip; ip += nE;
    int* eidS = ip; ip += nE;

    // conv2 buffers alias kbuf region (conv1 edge phase completes first)
    float* q2buf = kbuf;                       // tier>=1 only
    float* k2    = (tier >= 1) ? (kbuf + (size_t)n * 64)  : kbuf;
    float* v2    = (tier >= 1) ? (kbuf + (size_t)n * 128) : (kbuf + (size_t)n * 64);
    float* o2    = (tier >= 1) ? (kbuf + (size_t)n * 192) : (kbuf + (size_t)n * 128);

    const float sc1 = 1.0f / sqrtf(24.0f);
    const float sc2 = 1.0f / sqrtf(8.0f);
    const float* np = nullptr;
    float* npw = nullptr;

    // ---- CSR build ----
    zero2_kernel<<<(n + B - 1) / B, B, 0, stream>>>(cnt, cur, n);
    count_kernel<<<(nE + B - 1) / B, B, 0, stream>>>(dst, cnt, nE);
    scan_block_kernel<<<nb, 256, 0, stream>>>(cnt, bsum, n);
    scan_bsum_kernel<<<1, 1024, 0, stream>>>(bsum, nb);
    finalize_rp_kernel<<<(n + 1 + B - 1) / B, B, 0, stream>>>(cnt, bsum, rp, n, nE);
    scatter_kernel<<<(nE + B - 1) / B, B, 0, stream>>>(src, dst, rp, cur, srcS, eidS, nE);

    // ---- node MLP ----
    mlp_kernel<<<(n + B - 1) / B, B, 0, stream>>>(x, Aw, Ab, Bw, Bb, h1, n);

    const int gproj = (n + 31) / 32;

    // ---- conv1 projections + fused edge phase ----
    if (tier >= 1) {
        // k,v,s : 23 -> 192 x3 (WTOT=576, CG=72, block 576)
        proj_tiled_kernel<23, 23, 192, 3, 8><<<gproj, 576, 0, stream>>>(
            h1, n, k1w, k1b, kbuf, v1w, v1b, vbuf, s1w, s1b, o1, np, np, npw);
        if (tier == 2) {
            // q : 23 -> 192 (WTOT=192, CG=24, block 192) — removes the serial
            // 23-iteration q-recompute from conv1's latency-critical loop
            proj_tiled_kernel<23, 23, 192, 1, 8><<<gproj, 192, 0, stream>>>(
                h1, n, q1w, q1b, q1buf, np, np, npw, np, np, npw, np, np, npw);
            conv_fused_kernel<23, 24, true, true, true><<<(n + 3) / 4, 256, 0, stream>>>(
                h1, q1w, q1b, v1w, v1b, kbuf, vbuf, q1buf, ea, e1w, rp, srcS, eidS, o1, n, sc1);
        } else {
            conv_fused_kernel<23, 24, true, false, true><<<(n + 3) / 4, 256, 0, stream>>>(
                h1, q1w, q1b, v1w, v1b, kbuf, vbuf, np, ea, e1w, rp, srcS, eidS, o1, n, sc1);
        }
    } else {
        // k,s : 23 -> 192 x2 (WTOT=384, CG=48, block 384)
        proj_tiled_kernel<23, 23, 192, 2, 8><<<gproj, 384, 0, stream>>>(
            h1, n, k1w, k1b, kbuf, s1w, s1b, o1, np, np, npw, np, np, npw);
        conv_fused_kernel<23, 24, false, false, true><<<(n + 3) / 4, 256, 0, stream>>>(
            h1, q1w, q1b, v1w, v1b, kbuf, np, np, ea, e1w, rp, srcS, eidS, o1, n, sc1);
    }

    // ---- conv2 projections + fused edge phase ----
    if (tier >= 1) {
        // q,k,v,s : 192 -> 64 x4 (WTOT=256, CG=32, block 256)
        proj_tiled_kernel<192, 32, 64, 4, 8><<<gproj, 256, 0, stream>>>(
            o1, n, q2w, q2b, q2buf, k2w, k2b, k2, v2w, v2b, v2, s2w, s2b, o2);
        conv_fused_kernel<192, 8, true, true, false><<<(n + 3) / 4, 256, 0, stream>>>(
            o1, q2w, q2b, v2w, v2b, k2, v2, q2buf, ea, e2w, rp, srcS, eidS, o2, n, sc2);
    } else {
        proj_tiled_kernel<192, 32, 64, 3, 8><<<gproj, 192, 0, stream>>>(
            o1, n, k2w, k2b, k2, v2w, v2b, v2, s2w, s2b, o2, np, np, npw);
        conv_fused_kernel<192, 8, true, false, false><<<(n + 3) / 4, 256, 0, stream>>>(
            o1, q2w, q2b, v2w, v2b, k2, v2, np, ea, e2w, rp, srcS, eidS, o2, n, sc2);
    }

    // ---- head ----
    head_kernel<<<(n + B - 1) / B, B, 0, stream>>>(o2, l1w, l1b, l2w, l2b, out, n);
}